// Round 1
// baseline (87.358 us; speedup 1.0000x reference)
//
#include <hip/hip_runtime.h>

#define CAM_FL 540.0f
#define CAM_W  640
#define CAM_H  480
#define RADIUS 2
#define KSIZE  (2 * RADIUS + 1)   // 5
#define TAPS   (KSIZE * KSIZE)    // 25
#define BLK    256
#define NWAVE  (BLK / 64)         // 4 waves per block

// Single kernel: project -> PER-WAVE LDS compaction (ballot/rank, no block
// atomic, no barriers) -> tap-parallel splat within each wave.
// R2 lesson: no global counters (same-address global atomics ~28 cyc/op).
// R4 lesson: separable Gaussian -> 10 exps/survivor instead of 25.
// R5 (this round): waves are fully independent — each wave compacts its own
// survivors into a private LDS segment and splats them. Removes both
// __syncthreads, the s_cnt LDS atomic and the wbase shuffle. Within-wave
// LDS produce->consume is program-ordered (lockstep wave; compiler inserts
// the lgkmcnt wait on the may-aliasing ds_read).
__global__ __launch_bounds__(BLK) void particle_project_kernel(
    const float* __restrict__ locs,        // [B, N, 3]
    const float* __restrict__ camera_pose, // [B, 3]
    const float* __restrict__ camera_rot,  // [B, 4]
    const float* __restrict__ depth,       // [B, H, W]
    float* __restrict__ out,               // [B, H, W]
    int N)
{
#pragma clang fp contract(off)
    __shared__ int   s_iy0[NWAVE][64];
    __shared__ int   s_jx0[NWAVE][64];
    __shared__ float s_z  [NWAVE][64];
    __shared__ float s_wy [NWAVE][64][KSIZE];  // stride 5: gcd(5,32)=1 -> conflict-free
    __shared__ float s_wx [NWAVE][64][KSIZE];

    const int b    = blockIdx.y;
    const int tid  = threadIdx.x;
    const int wid  = tid >> 6;
    const int lane = tid & 63;
    const int n    = blockIdx.x * BLK + tid;

    // --- camera params (uniform within block -> scalarized) ---
    const float qx_raw = camera_rot[b * 4 + 0];
    const float qy_raw = camera_rot[b * 4 + 1];
    const float qz_raw = camera_rot[b * 4 + 2];
    const float qw_raw = camera_rot[b * 4 + 3];
    const float norm2 = ((qx_raw * qx_raw + qy_raw * qy_raw) + qz_raw * qz_raw) + qw_raw * qw_raw;
    const float s = sqrtf(norm2);
    const float qx = -(qx_raw / s);
    const float qy = -(qy_raw / s);
    const float qz = -(qz_raw / s);
    const float qw =  (qw_raw / s);

    const float qx2 = qx * qx, qy2 = qy * qy, qz2 = qz * qz;
    const float qxqy = qx * qy, qxqz = qx * qz, qxqw = qx * qw;
    const float qyqz = qy * qz, qyqw = qy * qw, qzqw = qz * qw;
    const float r00 = (1.0f - 2.0f * qy2) - 2.0f * qz2;
    const float r10 = 2.0f * qxqy - 2.0f * qzqw;
    const float r20 = 2.0f * qxqz + 2.0f * qyqw;
    const float r01 = 2.0f * qxqy + 2.0f * qzqw;
    const float r11 = (1.0f - 2.0f * qx2) - 2.0f * qz2;
    const float r21 = 2.0f * qyqz - 2.0f * qxqw;
    const float r02 = 2.0f * qxqz - 2.0f * qyqw;
    const float r12 = 2.0f * qyqz + 2.0f * qxqw;
    const float r22 = (1.0f - 2.0f * qx2) - 2.0f * qy2;

    const float cpx = camera_pose[b * 3 + 0];
    const float cpy = camera_pose[b * 3 + 1];
    const float cpz = camera_pose[b * 3 + 2];

    // --- projection (guarded loads) ---
    bool alive = (n < N);
    float px = 0.0f, py = 0.0f, z = 0.0f;
    if (alive) {
        const size_t base = (size_t)(b * N + n) * 3;
        // non-temporal: locs is streamed once; keep depth resident in L2
        const float l0 = __builtin_nontemporal_load(locs + base + 0);
        const float l1 = __builtin_nontemporal_load(locs + base + 1);
        const float l2 = __builtin_nontemporal_load(locs + base + 2);
        const float p0 = l0 - cpx;
        const float p1 = l1 - cpy;
        const float p2 = l2 - cpz;

        // p' = p . R, association order matches reference ((a+b)+c)
        const float x = (p0 * r00 + p1 * r10) + p2 * r20;
        const float y = (p0 * r01 + p1 * r11) + p2 * r21;
        z             = (p0 * r02 + p1 * r12) + p2 * r22;

        alive = (z > 0.0f);
        if (alive) {
            px = (x / z) * CAM_FL + (float)CAM_W * 0.5f;
            py = (y / z) * CAM_FL + (float)CAM_H * 0.5f;
            // float-domain frustum cull before any int conversion
            alive = (px >= -(float)RADIUS && px < (float)(CAM_W + RADIUS) &&
                     py >= -(float)RADIUS && py < (float)(CAM_H + RADIUS));
        }
    }

    // --- per-wave compaction: ballot + rank, no atomics, no barriers ---
    const unsigned long long mask = __ballot(alive);
    const int rank = __popcll(mask & ((1ull << lane) - 1ull));
    const int ns   = __popcll(mask);

    if (alive) {
        const int iy0 = (int)floorf(py);
        const int jx0 = (int)floorf(px);
        s_iy0[wid][rank] = iy0;
        s_jx0[wid][rank] = jx0;
        s_z  [wid][rank] = z;
        // separable Gaussian: 5 row weights + 5 col weights per survivor
#pragma unroll
        for (int k = 0; k < KSIZE; ++k) {
            const float dyf = (float)(iy0 + k - RADIUS) - py;
            const float dxf = (float)(jx0 + k - RADIUS) - px;
            s_wy[wid][rank][k] = __expf(-(dyf * dyf) * 0.5f);
            s_wx[wid][rank][k] = __expf(-(dxf * dxf) * 0.5f);
        }
    }

    // --- tap-parallel splat over this wave's survivors ---
    const int total = ns * TAPS;
    const float* depth_b = depth + (size_t)b * (CAM_H * CAM_W);
    float*       out_b   = out   + (size_t)b * (CAM_H * CAM_W);

    for (int t = lane; t < total; t += 64) {
        const int si  = t / TAPS;            // magic-mul const division
        const int tap = t - si * TAPS;
        const int ti  = tap / KSIZE;
        const int tj  = tap - ti * KSIZE;

        // 25 consecutive lanes share one survivor -> LDS broadcasts
        const int iy = s_iy0[wid][si] + ti - RADIUS;
        const int jx = s_jx0[wid][si] + tj - RADIUS;
        if ((unsigned)iy >= (unsigned)CAM_H || (unsigned)jx >= (unsigned)CAM_W)
            continue;

        const int pix = iy * CAM_W + jx;
        const float d = depth_b[pix];
        if (s_z[wid][si] <= d) {
            const float w = s_wy[wid][si][ti] * s_wx[wid][si][tj];
            atomicAdd(&out_b[pix], w);
        }
    }
}

extern "C" void kernel_launch(void* const* d_in, const int* in_sizes, int n_in,
                              void* d_out, int out_size, void* d_ws, size_t ws_size,
                              hipStream_t stream) {
    const float* locs        = (const float*)d_in[0];
    const float* camera_pose = (const float*)d_in[1];
    const float* camera_rot  = (const float*)d_in[2];
    const float* depth_mask  = (const float*)d_in[3];
    float* out = (float*)d_out;

    const int B = in_sizes[1] / 3;             // camera_pose is [B,3]
    const int N = in_sizes[0] / (3 * B);       // locs is [B,N,3]

    // harness poisons d_out with 0xAA before every timed launch
    hipMemsetAsync(d_out, 0, (size_t)out_size * sizeof(float), stream);

    dim3 block(BLK, 1, 1);
    dim3 grid((N + BLK - 1) / BLK, B, 1);
    particle_project_kernel<<<grid, block, 0, stream>>>(
        locs, camera_pose, camera_rot, depth_mask, out, N);
}